// Round 3
// baseline (112.667 us; speedup 1.0000x reference)
//
#include <hip/hip_runtime.h>

// MinimalAdderNN: base-10 ripple-carry adder -> one-hot logits [BATCH, 11, 10] f32.
// Tables replaced by arithmetic. R3 strategy: NO LDS image. Phase 1 packs each
// row's 11 digits into two u32 nibble-words in LDS (1 KB/block). Phase 2 is a
// coalesced float4 store stream where each element's value is recomputed from
// the packed digits with incremental (row, rem) bookkeeping -- no runtime
// division, no big LDS, high occupancy -> stores run at the HBM ceiling.

#define ROWS 128
#define THREADS 256
#define FPR 110  // floats per row: 11 positions * 10 slots

__global__ __launch_bounds__(THREADS) void adder_onehot_kernel(
    const int* __restrict__ a, const int* __restrict__ b,
    float* __restrict__ out, int batch) {
    __shared__ uint2 packed[ROWS + 1];  // +1 pad: speculative row+1 read stays in-bounds

    const int t = threadIdx.x;
    const int row0 = blockIdx.x * ROWS;

    // ---- Phase 1: threads 0..127 compute + nibble-pack their row's digits ----
    if (t < ROWS && row0 + t < batch) {
        const int* ap = a + (size_t)(row0 + t) * 10;
        const int* bp = b + (size_t)(row0 + t) * 10;
        int av[10], bv[10];
#pragma unroll
        for (int p = 0; p < 10; ++p) av[p] = ap[p];
#pragma unroll
        for (int p = 0; p < 10; ++p) bv[p] = bp[p];

        int dig[11];
        int carry = 0;
#pragma unroll
        for (int p = 9; p >= 0; --p) {  // LSD first
            int tot = av[p] + bv[p] + carry;
            int c = tot >= 10;
            dig[1 + p] = c ? tot - 10 : tot;  // output position 1+p
            carry = c;
        }
        dig[0] = carry;  // leading one-hot position

        unsigned w0 = 0, w1 = 0;
#pragma unroll
        for (int pos = 0; pos < 8; ++pos) w0 |= (unsigned)dig[pos] << (4 * pos);
#pragma unroll
        for (int pos = 8; pos < 11; ++pos) w1 |= (unsigned)dig[pos] << (4 * (pos - 8));
        packed[t] = make_uint2(w0, w1);
    }
    __syncthreads();

    // ---- Phase 2: coalesced float4 store stream, values from packed digits ----
    const int rows_here = min(ROWS, batch - row0);
    const int total_f = rows_here * FPR;
    const int nvec = total_f >> 2;
    float4* out4 = (float4*)(out + (size_t)row0 * FPR);  // row0 % 4 == 0 -> 16B aligned

    // Per-thread incremental divmod state: element e = 4*i, i = t + 256k.
    // Step: e += 1024 = 9*110 + 34  =>  row += 9, rem += 34, wrap once max.
    int e0 = 4 * t;
    int row = e0 / 110;        // compile-time magic mul, once
    int rem = e0 - 110 * row;

    for (int i = t; i < nvec; i += THREADS) {
        uint2 p0 = packed[row];
        uint2 p1 = packed[row + 1];  // speculative; selected only when rem+k >= 110
        float4 v;
        float* vp = &v.x;
#pragma unroll
        for (int k = 0; k < 4; ++k) {
            int re = rem + k;
            bool wrap = re >= 110;
            int re2 = wrap ? re - 110 : re;
            unsigned wlo = wrap ? p1.x : p0.x;
            unsigned whi = wrap ? p1.y : p0.y;
            int pos = (re2 * 205) >> 11;       // re2/10 for 0..109
            int slot = re2 - 10 * pos;
            unsigned w = (pos >= 8) ? whi : wlo;
            int digit = (w >> ((pos & 7) * 4)) & 15;
            vp[k] = (digit == slot) ? 1.0f : 0.0f;
        }
        out4[i] = v;

        row += 9;
        rem += 34;
        if (rem >= 110) { rem -= 110; ++row; }
    }

    // Scalar tail (none for batch=2^20: rows_here*110 % 4 == 0), kept for generality.
    const int tail0 = nvec * 4;
    if (t < total_f - tail0) {
        int e = tail0 + t;
        int r = e / 110;
        int re2 = e - 110 * r;
        int pos = (re2 * 205) >> 11;
        int slot = re2 - 10 * pos;
        uint2 pw = packed[r];
        unsigned w = (pos >= 8) ? pw.y : pw.x;
        int digit = (w >> ((pos & 7) * 4)) & 15;
        out[(size_t)row0 * FPR + e] = (digit == slot) ? 1.0f : 0.0f;
    }
}

extern "C" void kernel_launch(void* const* d_in, const int* in_sizes, int n_in,
                              void* d_out, int out_size, void* d_ws, size_t ws_size,
                              hipStream_t stream) {
    const int* a = (const int*)d_in[0];
    const int* b = (const int*)d_in[1];
    // d_in[2]/d_in[3] (lookup tables) are deterministic -> replaced by arithmetic.
    float* out = (float*)d_out;
    const int batch = in_sizes[0] / 10;

    const int grid = (batch + ROWS - 1) / ROWS;
    adder_onehot_kernel<<<grid, THREADS, 0, stream>>>(a, b, out, batch);
}